// Round 1
// baseline (71.377 us; speedup 1.0000x reference)
//
#include <hip/hip_runtime.h>
#include <math.h>

#define N 16384
#define K 32
#define D 16
#define S 2048
#define E 500000
#define EPSF 1e-6f

// ---- workspace layout (float offsets) ----
#define OFF_Z      0                       // K*N
#define OFF_ZTG    (OFF_Z + K*N)           // N*K
#define OFF_COLSUM (OFF_ZTG + N*K)         // 32
#define OFF_MPART  (OFF_COLSUM + 32)       // 32*1024
#define OFF_AZC    (OFF_MPART + 32*1024)   // 512
#define OFF_X      (OFF_AZC + 512)         // N*D
#define OFF_PD1    (OFF_X + N*D)           // 256
#define OFF_PD2    (OFF_PD1 + 256)         // 240
// total ~1.35M floats ~5.3 MB

__device__ __forceinline__ float block_reduce_sum(float v, float* sdata) {
    int tid = threadIdx.x;
    sdata[tid] = v;
    __syncthreads();
    for (int s = blockDim.x >> 1; s > 0; s >>= 1) {
        if (tid < s) sdata[tid] += sdata[tid + s];
        __syncthreads();
    }
    return sdata[0];
}

// K1: Z = softmax(Zp, axis=0) ; ZTG = Z.T * sigmoid(Gate)
__global__ __launch_bounds__(256) void k1_softmax_ztg(
    const float* __restrict__ Zp, const float* __restrict__ Gate,
    float* __restrict__ ws) {
    int n = blockIdx.x * 256 + threadIdx.x;
    float z[K];
    float m = -1e30f;
#pragma unroll
    for (int k = 0; k < K; ++k) { z[k] = Zp[k * N + n]; m = fmaxf(m, z[k]); }
    float s = 0.f;
#pragma unroll
    for (int k = 0; k < K; ++k) { z[k] = expf(z[k] - m); s += z[k]; }
    float inv = 1.f / s;
#pragma unroll
    for (int k = 0; k < K; ++k) {
        z[k] *= inv;
        ws[OFF_Z + k * N + n] = z[k];
    }
    const float4* gp = reinterpret_cast<const float4*>(Gate + (size_t)n * K);
    float4* tp = reinterpret_cast<float4*>(ws + OFF_ZTG + (size_t)n * K);
#pragma unroll
    for (int q = 0; q < K / 4; ++q) {
        float4 g = gp[q];
        float4 o;
        o.x = z[4 * q + 0] * (1.f / (1.f + expf(-g.x)));
        o.y = z[4 * q + 1] * (1.f / (1.f + expf(-g.y)));
        o.z = z[4 * q + 2] * (1.f / (1.f + expf(-g.z)));
        o.w = z[4 * q + 3] * (1.f / (1.f + expf(-g.w)));
        tp[q] = o;
    }
}

// K23: blocks 0..31 -> colsum[k] = sum_n ZTG[n][k]
//      blocks 32..63 -> Mpart[cb][a][b] = sum over 64 samples of Z[a,idx]*ZTG[idx,b]
__global__ __launch_bounds__(256) void k23_colsum_mpart(
    const int* __restrict__ sample_idx, float* __restrict__ ws) {
    __shared__ float sdata[256];
    __shared__ float sZ[64][K];
    __shared__ float sT[64][K];
    __shared__ int sidx[64];
    int bid = blockIdx.x, tid = threadIdx.x;
    if (bid < 32) {
        int k = bid;
        float acc = 0.f;
        for (int n = tid; n < N; n += 256) acc += ws[OFF_ZTG + (size_t)n * K + k];
        float tot = block_reduce_sum(acc, sdata);
        if (tid == 0) ws[OFF_COLSUM + k] = tot;
    } else {
        int cb = bid - 32;
        if (tid < 64) sidx[tid] = sample_idx[cb * 64 + tid];
        __syncthreads();
        for (int q = tid; q < 64 * K; q += 256) {
            int sloc = q >> 5, a = q & 31;
            int idx = sidx[sloc];
            sZ[sloc][a] = ws[OFF_Z + (size_t)a * N + idx];
            sT[sloc][a] = ws[OFF_ZTG + (size_t)idx * K + a];
        }
        __syncthreads();
#pragma unroll
        for (int e4 = 0; e4 < 4; ++e4) {
            int ent = tid + e4 * 256;
            int a = ent >> 5, b = ent & 31;
            float acc = 0.f;
            for (int sloc = 0; sloc < 64; ++sloc) acc += sZ[sloc][a] * sT[sloc][b];
            ws[OFF_MPART + cb * 1024 + ent] = acc;
        }
    }
}

// K4: M = (sum Mpart)/colsum ; AZC = A @ M  (D x K)
__global__ __launch_bounds__(1024) void k4_reduce_azc(
    const float* __restrict__ A, float* __restrict__ ws) {
    __shared__ float sM[1024];
    int t = threadIdx.x;
    float acc = 0.f;
#pragma unroll
    for (int p = 0; p < 32; ++p) acc += ws[OFF_MPART + p * 1024 + t];
    int b = t & 31;
    sM[t] = acc / ws[OFF_COLSUM + b];
    __syncthreads();
    if (t < D * K) {
        int d = t >> 5, bb = t & 31;
        float a2 = 0.f;
#pragma unroll
        for (int a = 0; a < K; ++a) a2 += A[d * K + a] * sM[a * 32 + bb];
        ws[OFF_AZC + t] = a2;
    }
}

// K5: X[n][d] = sum_k AZC[d][k] * Z[k][n]
__global__ __launch_bounds__(256) void k5_x(float* __restrict__ ws) {
    __shared__ float sA[512];
    int tid = threadIdx.x;
    sA[tid] = ws[OFF_AZC + tid];
    sA[tid + 256] = ws[OFF_AZC + tid + 256];
    __syncthreads();
    int n = blockIdx.x * 256 + tid;
    float x[D];
#pragma unroll
    for (int d = 0; d < D; ++d) x[d] = 0.f;
#pragma unroll
    for (int k = 0; k < K; ++k) {
        float zk = ws[OFF_Z + (size_t)k * N + n];
#pragma unroll
        for (int d = 0; d < D; ++d) x[d] = fmaf(sA[d * 32 + k], zk, x[d]);
    }
    float4* xp = reinterpret_cast<float4*>(ws + OFF_X + (size_t)n * D);
#pragma unroll
    for (int q = 0; q < D / 4; ++q) {
        float4 o; o.x = x[4*q]; o.y = x[4*q+1]; o.z = x[4*q+2]; o.w = x[4*q+3];
        xp[q] = o;
    }
}

// K67: blocks 0..255 -> pairwise exp sum (8 rows each)
//      blocks 256..495 -> sparse-edge sum
__global__ __launch_bounds__(256) void k67_pdist(
    const float* __restrict__ beta, const int* __restrict__ sample_idx,
    const int* __restrict__ sparse_i, const int* __restrict__ sparse_j,
    float* __restrict__ ws) {
    __shared__ float sdata[256];
    __shared__ float sXr[8][D];
    __shared__ float sbr[8];
    int bid = blockIdx.x, tid = threadIdx.x;
    const float* X = ws + OFF_X;
    float acc = 0.f;
    if (bid < 256) {
        int r0 = bid * 8;
        if (tid < 8 * D) {
            int r = tid >> 4, d = tid & 15;
            int idx = sample_idx[r0 + r];
            sXr[r][d] = X[(size_t)idx * D + d];
            if (d == 0) sbr[r] = beta[idx];
        }
        __syncthreads();
        for (int t = tid; t < S; t += 256) {
            int st = sample_idx[t];
            const float4* xp = reinterpret_cast<const float4*>(X + (size_t)st * D);
            float xt[D];
#pragma unroll
            for (int q = 0; q < D / 4; ++q) {
                float4 v = xp[q];
                xt[4*q] = v.x; xt[4*q+1] = v.y; xt[4*q+2] = v.z; xt[4*q+3] = v.w;
            }
            float bt = beta[st];
#pragma unroll
            for (int r = 0; r < 8; ++r) {
                float d2 = 0.f;
#pragma unroll
                for (int d = 0; d < D; ++d) {
                    float df = sXr[r][d] - xt[d] + EPSF;
                    d2 = fmaf(df, df, d2);
                }
                float v = expf(sbr[r] + bt - sqrtf(d2));
                acc += (r0 + r == t) ? 0.f : v;
            }
        }
    } else {
        int eb = bid - 256;
        for (int e = eb * 256 + tid; e < E; e += 240 * 256) {
            int i = sparse_i[e], j = sparse_j[e];
            const float4* xi = reinterpret_cast<const float4*>(X + (size_t)i * D);
            const float4* xj = reinterpret_cast<const float4*>(X + (size_t)j * D);
            float d2 = 0.f;
#pragma unroll
            for (int q = 0; q < D / 4; ++q) {
                float4 a4 = xi[q], b4 = xj[q];
                float df;
                df = a4.x - b4.x + EPSF; d2 = fmaf(df, df, d2);
                df = a4.y - b4.y + EPSF; d2 = fmaf(df, df, d2);
                df = a4.z - b4.z + EPSF; d2 = fmaf(df, df, d2);
                df = a4.w - b4.w + EPSF; d2 = fmaf(df, df, d2);
            }
            acc += beta[i] + beta[j] - sqrtf(d2);
        }
    }
    __syncthreads();
    float tot = block_reduce_sum(acc, sdata);
    if (tid == 0) {
        if (bid < 256) ws[OFF_PD1 + bid] = tot;
        else ws[OFF_PD2 + (bid - 256)] = tot;
    }
}

// K8: final scalar
__global__ __launch_bounds__(256) void k8_final(float* __restrict__ ws,
                                                float* __restrict__ out) {
    __shared__ float sdata[256];
    int tid = threadIdx.x;
    float s1 = block_reduce_sum(ws[OFF_PD1 + tid], sdata);
    __syncthreads();
    float v2 = (tid < 240) ? ws[OFF_PD2 + tid] : 0.f;
    float s2 = block_reduce_sum(v2, sdata);
    if (tid == 0) {
        float e = expf(1.0f);
        out[0] = s2 - 0.5f * e * e * s1;
    }
}

extern "C" void kernel_launch(void* const* d_in, const int* in_sizes, int n_in,
                              void* d_out, int out_size, void* d_ws, size_t ws_size,
                              hipStream_t stream) {
    const float* beta = (const float*)d_in[0];
    const float* A    = (const float*)d_in[1];
    const float* Zp   = (const float*)d_in[2];
    const float* Gate = (const float*)d_in[3];
    const int* sample_idx = (const int*)d_in[4];
    const int* sparse_i   = (const int*)d_in[5];
    const int* sparse_j   = (const int*)d_in[6];
    float* ws  = (float*)d_ws;
    float* out = (float*)d_out;

    k1_softmax_ztg<<<N / 256, 256, 0, stream>>>(Zp, Gate, ws);
    k23_colsum_mpart<<<64, 256, 0, stream>>>(sample_idx, ws);
    k4_reduce_azc<<<1, 1024, 0, stream>>>(A, ws);
    k5_x<<<N / 256, 256, 0, stream>>>(ws);
    k67_pdist<<<496, 256, 0, stream>>>(beta, sample_idx, sparse_i, sparse_j, ws);
    k8_final<<<1, 256, 0, stream>>>(ws, out);
}